// Round 1
// baseline (473.492 us; speedup 1.0000x reference)
//
#include <hip/hip_runtime.h>
#include <stdint.h>

// Problem constants
#define N_ 64
#define C_ 64
#define O_ 128
#define T_ 300
#define V_ 25
#define TB 4            // t-groups per block (divides 300)
#define JB (TB * 32)    // 128 padded j-columns (each t padded 25->32)
#define KB 128          // GEMM K: k<64 raw x (residual), k>=64 xa (main)
#define LDB 136         // LDS B row stride in bf16 elements (pad 8 vs 128)

typedef __attribute__((ext_vector_type(8))) short short8;
typedef __attribute__((ext_vector_type(4))) float floatx4;

__device__ __forceinline__ short f2bf(float f) {
  // round-to-nearest-even fp32 -> bf16 bits
  unsigned u = __float_as_uint(f);
  unsigned r = (u + 0x7FFFu + ((u >> 16) & 1u)) >> 16;
  return (short)(r & 0xFFFFu);
}

// ---------------- prep: fold BN into weights, build M2 = A*edge, bias table ----
__global__ void sgc_prep(const float* __restrict__ A, const float* __restrict__ edge,
                         const float* __restrict__ gcn_w, const float* __restrict__ gcn_b,
                         const float* __restrict__ bn_g, const float* __restrict__ bn_b,
                         const float* __restrict__ bn_m, const float* __restrict__ bn_v,
                         const float* __restrict__ res_w, const float* __restrict__ res_b,
                         const float* __restrict__ rg, const float* __restrict__ rb,
                         const float* __restrict__ rm, const float* __restrict__ rv,
                         short* __restrict__ Wcat, float* __restrict__ M2p,
                         float* __restrict__ Cwp) {
  const int tid = threadIdx.x;
  // M2p[v][w], stride 32, pad cols w>=25 are 0
  for (int i = tid; i < 25 * 32; i += 256) {
    const int v = i >> 5, w = i & 31;
    M2p[i] = (w < 25) ? A[v * 25 + w] * edge[v * 25 + w] : 0.f;
  }
  // Cw[o][w] = inv1*gcn_b*S[w] + (bn_b - bn_m*inv1) + inv2*res_b + (rb - rm*inv2)
  for (int i = tid; i < O_ * 32; i += 256) {
    const int o = i >> 5, w = i & 31;
    const float inv1 = bn_g[o] * rsqrtf(bn_v[o] + 1e-5f);
    const float inv2 = rg[o] * rsqrtf(rv[o] + 1e-5f);
    float S = 0.f;
    if (w < 25) {
      for (int v = 0; v < 25; ++v) S += A[v * 25 + w] * edge[v * 25 + w];
    }
    Cwp[i] = inv1 * gcn_b[o] * S + (bn_b[o] - bn_m[o] * inv1) + inv2 * res_b[o] +
             (rb[o] - rm[o] * inv2);
  }
  // Wcat bf16 [o][k]: k<64 -> inv2*res_w (pairs raw x rows), k>=64 -> inv1*gcn_w (pairs xa rows)
  for (int i = tid; i < O_ * KB; i += 256) {
    const int o = i >> 7, k = i & 127;
    const float inv1 = bn_g[o] * rsqrtf(bn_v[o] + 1e-5f);
    const float inv2 = rg[o] * rsqrtf(rv[o] + 1e-5f);
    const float val = (k < 64) ? inv2 * res_w[o * 64 + k] : inv1 * gcn_w[o * 64 + (k - 64)];
    Wcat[i] = f2bf(val);
  }
}

// ---------------- main fused kernel -------------------------------------------
// grid: 64 n * 75 t-blocks; block: 256 threads (4 waves)
__global__ __launch_bounds__(256, 2) void sgc_main(const float* __restrict__ x,
                                                   const short* __restrict__ Wcat,
                                                   const float* __restrict__ M2p,
                                                   const float* __restrict__ Cw,
                                                   float* __restrict__ out) {
  __shared__ short Bs[JB * LDB];  // 128 j-rows x 136 k -> 34816 B
  const int tid = threadIdx.x;
  const int b = blockIdx.x;
  const int n = b / 75;
  const int t0 = (b % 75) * TB;

  // ---- phase 1: load x row, compute xa = x @ M2, build bf16 B in LDS ----
  {
    const int tl = tid >> 6;  // wave == local t (bank-friendly scatter: c across lanes)
    const int c = tid & 63;
    const float* xrow = x + (((n * C_ + c) * T_) + (t0 + tl)) * V_;
    float xr[25];
#pragma unroll
    for (int v = 0; v < 25; ++v) xr[v] = xrow[v];
    // raw x rows: B[j = tl*32+v][k = c]
#pragma unroll
    for (int v = 0; v < 25; ++v) Bs[(tl * 32 + v) * LDB + c] = f2bf(xr[v]);
    // zero the per-t pad columns (j = tl*32 + 25..31) for both k halves
#pragma unroll
    for (int v = 25; v < 32; ++v) {
      Bs[(tl * 32 + v) * LDB + c] = 0;
      Bs[(tl * 32 + v) * LDB + 64 + c] = 0;
    }
    // xa[w] = sum_v x[v] * M2[v][w]  (M2 reads are wave-uniform -> scalar loads)
    float xa[25];
#pragma unroll
    for (int w = 0; w < 25; ++w) xa[w] = 0.f;
    for (int v = 0; v < 25; ++v) {
      const float xv = xr[v];
      const float* m2 = M2p + v * 32;
#pragma unroll
      for (int w = 0; w < 25; ++w) xa[w] = __builtin_fmaf(xv, m2[w], xa[w]);
    }
#pragma unroll
    for (int w = 0; w < 25; ++w) Bs[(tl * 32 + w) * LDB + 64 + c] = f2bf(xa[w]);
  }
  __syncthreads();

  // ---- phase 2: MFMA  D[o][j] = Wcat[o][k] * B[k][j] ----
  const int lane = tid & 63;
  const int wv = tid >> 6;
  const int l15 = lane & 15;
  const int quad = lane >> 4;
  const int obase = wv * 32;  // each wave: 32 o-rows (2 M-tiles) x all 128 j

  // A-frags from global (L2-hot): A[m=l15][k=quad*8+jj]
  short8 af[2][4];
#pragma unroll
  for (int mt = 0; mt < 2; ++mt) {
#pragma unroll
    for (int kq = 0; kq < 4; ++kq) {
      af[mt][kq] =
          *(const short8*)(Wcat + (obase + mt * 16 + l15) * KB + kq * 32 + quad * 8);
    }
  }

  floatx4 acc[2][8];
#pragma unroll
  for (int mt = 0; mt < 2; ++mt)
#pragma unroll
    for (int jt = 0; jt < 8; ++jt) acc[mt][jt] = (floatx4){0.f, 0.f, 0.f, 0.f};

#pragma unroll
  for (int jt = 0; jt < 8; ++jt) {
#pragma unroll
    for (int kq = 0; kq < 4; ++kq) {
      // B-frag: B[k=quad*8+jj][n=j]  -> 16 contiguous bf16 from LDS
      const short8 bf =
          *(const short8*)(&Bs[(jt * 16 + l15) * LDB + kq * 32 + quad * 8]);
      acc[0][jt] = __builtin_amdgcn_mfma_f32_16x16x32_bf16(af[0][kq], bf, acc[0][jt], 0, 0, 0);
      acc[1][jt] = __builtin_amdgcn_mfma_f32_16x16x32_bf16(af[1][kq], bf, acc[1][jt], 0, 0, 0);
    }
  }

  // ---- epilogue: + Cw, relu, store (C/D: col=l15 -> j, row=quad*4+r -> o) ----
#pragma unroll
  for (int mt = 0; mt < 2; ++mt) {
#pragma unroll
    for (int jt = 0; jt < 8; ++jt) {
      const int j = jt * 16 + l15;
      const int w = j & 31;
      if (w < 25) {
        const int tloc = j >> 5;
        const int o0 = obase + mt * 16 + quad * 4;
        float* op = out + (((n * O_ + o0) * T_) + (t0 + tloc)) * V_ + w;
        const float* cwp = Cw + o0 * 32 + w;
#pragma unroll
        for (int r = 0; r < 4; ++r) {
          const float val = acc[mt][jt][r] + cwp[r * 32];
          op[r * (T_ * V_)] = val > 0.f ? val : 0.f;
        }
      }
    }
  }
}

extern "C" void kernel_launch(void* const* d_in, const int* in_sizes, int n_in,
                              void* d_out, int out_size, void* d_ws, size_t ws_size,
                              hipStream_t stream) {
  const float* x = (const float*)d_in[0];
  const float* A = (const float*)d_in[1];
  const float* edge = (const float*)d_in[2];
  const float* gcn_w = (const float*)d_in[3];
  const float* gcn_b = (const float*)d_in[4];
  const float* bn_g = (const float*)d_in[5];
  const float* bn_b = (const float*)d_in[6];
  const float* bn_m = (const float*)d_in[7];
  const float* bn_v = (const float*)d_in[8];
  const float* res_w = (const float*)d_in[9];
  const float* res_b = (const float*)d_in[10];
  const float* rg = (const float*)d_in[11];
  const float* rb = (const float*)d_in[12];
  const float* rm = (const float*)d_in[13];
  const float* rv = (const float*)d_in[14];

  char* ws = (char*)d_ws;
  short* Wcat = (short*)(ws);          // 32768 B
  float* M2p = (float*)(ws + 32768);   // 3200 B
  float* Cwp = (float*)(ws + 36864);   // 16384 B
  float* out = (float*)d_out;

  hipLaunchKernelGGL(sgc_prep, dim3(1), dim3(256), 0, stream, A, edge, gcn_w, gcn_b,
                     bn_g, bn_b, bn_m, bn_v, res_w, res_b, rg, rb, rm, rv, Wcat, M2p, Cwp);
  hipLaunchKernelGGL(sgc_main, dim3(N_ * (T_ / TB)), dim3(256), 0, stream, x, Wcat, M2p,
                     Cwp, out);
}